// Round 6
// baseline (3339.507 us; speedup 1.0000x reference)
//
#include <hip/hip_runtime.h>
#include <math.h>

#define TPB 256
#define EPSF 1e-6f
#define LOG_G1 -2.3025850929940457f   /* log(0.1) */
#define LOGEPS -13.815510557964274f   /* log(1e-6) */
#define NEG_INF_KEY 0x007FFFFFu       /* f2key(-inf) */

// order-preserving float<->uint map
__device__ __forceinline__ unsigned f2key(float x){
  unsigned u = __float_as_uint(x);
  return (u & 0x80000000u) ? ~u : (u | 0x80000000u);
}
__device__ __forceinline__ float key2f(unsigned k){
  return (k & 0x80000000u) ? __uint_as_float(k & 0x7fffffffu)
                           : __uint_as_float(~k);
}
__device__ __forceinline__ float score_from(float gt, float c, float t0){
  float g0 = fmaxf(c, EPSF);
  float dt = t0 - gt;
  // log(max(exp(sigma*dt^2),EPS))/T == max(sigma*dt^2, logEPS)/T exactly
  return fmaxf(LOG_G1 / (g0 * g0 + EPSF) * dt * dt, LOGEPS) / 0.07f;
}

// ---------------- init per-voxel state ----------------
__global__ void k_init(unsigned* __restrict__ mkey, unsigned* __restrict__ mopkey,
                       float* __restrict__ sumex, float* __restrict__ inv,
                       float* __restrict__ agg, int M){
  int v = blockIdx.x * TPB + threadIdx.x;
  if (v < M){
    mkey[v]   = NEG_INF_KEY;
    mopkey[v] = NEG_INF_KEY;
    sumex[v]  = 0.0f;
    inv[v]    = 0.0f;
  }
  size_t total = (size_t)M * 14;
  for (size_t i = (size_t)blockIdx.x * TPB + threadIdx.x; i < total;
       i += (size_t)gridDim.x * TPB)
    agg[i] = 0.0f;
}

// ---------------- pass 1: score (linear) + segment max (fire-and-forget) ----------------
__global__ __launch_bounds__(TPB)
void k_score(const float* __restrict__ feat, const float* __restrict__ conf,
             const int* __restrict__ vox, const float* __restrict__ tt,
             float* __restrict__ S, unsigned* __restrict__ mkey, int N){
  int i = blockIdx.x * TPB + threadIdx.x;
  if (i >= N) return;
  float s = score_from(feat[(size_t)i * 15 + 14], conf[i], tt[0]);
  S[i] = s;
  atomicMax(&mkey[vox[i]], f2key(s));        // no return use -> fire-and-forget
}

// ---------------- pass 2: ex (linear) + segment sum (fire-and-forget) ----------------
__global__ __launch_bounds__(TPB)
void k_sumex(const int* __restrict__ vox, const unsigned* __restrict__ mkey,
             float* __restrict__ SW /* in: score, out: ex */,
             float* __restrict__ sumex, int N){
  int i = blockIdx.x * TPB + threadIdx.x;
  if (i >= N) return;
  int v = vox[i];
  float ex = expf(SW[i] - key2f(mkey[v]));   // mkey: 0.5MB, L2-resident gather
  SW[i] = ex;
  unsafeAtomicAdd(&sumex[v], ex);            // no return use -> fire-and-forget
}

// ---------------- pass 3: weighted agg into 14 transposed L2-resident planes ----------------
__global__ __launch_bounds__(TPB)
void k_agg(const float* __restrict__ feat, const int* __restrict__ vox,
           const float* __restrict__ EX, float* __restrict__ agg,
           unsigned* __restrict__ mopkey, int M, int N){
  __shared__ float sf[TPB * 15];
  int base = blockIdx.x * TPB;
  int nrow = N - base; if (nrow > TPB) nrow = TPB;
  int nflt = nrow * 15;
  if (nflt == TPB * 15){
    const float4* g4 = (const float4*)(feat + (size_t)base * 15);
    float4* s4 = (float4*)sf;
    #pragma unroll
    for (int k = 0; k < 4; ++k){
      int j = threadIdx.x + k * TPB;
      if (j < TPB * 15 / 4) s4[j] = g4[j];
    }
  } else {
    for (int j = threadIdx.x; j < nflt; j += TPB)
      sf[j] = feat[(size_t)base * 15 + j];
  }
  __syncthreads();
  int t = threadIdx.x;
  if (t >= nrow) return;
  int i = base + t;
  float r[14];
  #pragma unroll
  for (int c = 0; c < 14; ++c) r[c] = sf[t * 15 + c];   // stride 15: conflict-free
  float ex = EX[i];                                     // linear
  int   v  = vox[i];
  float r6 = r[6];
  r[7] = logf(fmaxf(r[7], 1e-6f));
  r[8] = logf(fmaxf(r[8], 1e-6f));
  r[9] = logf(fmaxf(r[9], 1e-6f));
  // 14 fire-and-forget adds, each to a DIFFERENT 0.5MB plane (different L2 line/channel)
  #pragma unroll
  for (int c = 0; c < 14; ++c)
    unsafeAtomicAdd(&agg[(size_t)c * M + v], r[c] * ex);
  atomicMax(&mopkey[v], f2key(r6));                     // fire-and-forget
}

// ---------------- pass 4: per-voxel finalize (all linear) ----------------
__global__ __launch_bounds__(TPB)
void k_final(const unsigned* __restrict__ mkey, const unsigned* __restrict__ mopkey,
             const float* __restrict__ sumex, const float* __restrict__ agg,
             float* __restrict__ F, float* __restrict__ inv, int M){
  int v = blockIdx.x * TPB + threadIdx.x;
  if (v >= M) return;
  bool  has = mkey[v] != NEG_INF_KEY;
  float iv  = has ? 1.0f / sumex[v] : 0.0f;
  inv[v] = iv;
  float a[14];
  #pragma unroll
  for (int c = 0; c < 14; ++c) a[c] = agg[(size_t)c * M + v] * iv;  // per-plane coalesced
  float maxop = has ? key2f(mopkey[v]) : 0.0f;
  float r0 = a[10], r1 = a[11], r2 = a[12], r3 = a[13];
  float nrm  = sqrtf(r0*r0 + r1*r1 + r2*r2 + r3*r3);
  float rinv = 1.0f / fmaxf(nrm, 1e-6f);
  float* f = F + (size_t)v * 15;
  f[0] = a[0]; f[1] = a[1]; f[2] = a[2];
  f[3] = a[3]; f[4] = a[4]; f[5] = a[5];
  f[6] = 0.7f * maxop + 0.3f * a[6];
  f[7] = expf(a[7]); f[8] = expf(a[8]); f[9] = expf(a[9]);
  f[10] = r0 * rinv; f[11] = r1 * rinv; f[12] = r2 * rinv; f[13] = r3 * rinv;
  f[14] = 0.0f;
}

// ---------------- pass 5: normalize weights (linear + L2 gather) ----------------
__global__ __launch_bounds__(TPB)
void k_wnorm(const int* __restrict__ vox, const float* __restrict__ inv,
             float* __restrict__ W, int N){
  int i = blockIdx.x * TPB + threadIdx.x;
  if (i >= N) return;
  W[i] = W[i] * inv[vox[i]];     // W held ex
}

extern "C" void kernel_launch(void* const* d_in, const int* in_sizes, int n_in,
                              void* d_out, int out_size, void* d_ws, size_t ws_size,
                              hipStream_t stream) {
  const float* feat = (const float*)d_in[0];
  const int*   vox  = (const int*)  d_in[1];
  const float* tt   = (const float*)d_in[3];
  const float* conf = (const float*)d_in[4];

  int N = in_sizes[0] / 15;
  int M = (out_size - N) / 15;

  float* F = (float*)d_out;                      // fused gaussians: M*15
  float* W = (float*)d_out + (size_t)M * 15;     // weights: N (score -> ex -> w)

  unsigned* mkey   = (unsigned*)d_ws;            // M
  unsigned* mopkey = mkey + M;                   // M
  float*    sumex  = (float*)(mopkey + M);       // M
  float*    inv    = sumex + M;                  // M
  float*    agg    = inv + M;                    // 14*M (transposed planes)

  int gM = (M + TPB - 1) / TPB;
  int gN = (N + TPB - 1) / TPB;

  k_init <<<gM, TPB, 0, stream>>>(mkey, mopkey, sumex, inv, agg, M);
  k_score<<<gN, TPB, 0, stream>>>(feat, conf, vox, tt, W, mkey, N);
  k_sumex<<<gN, TPB, 0, stream>>>(vox, mkey, W, sumex, N);
  k_agg  <<<gN, TPB, 0, stream>>>(feat, vox, W, agg, mopkey, M, N);
  k_final<<<gM, TPB, 0, stream>>>(mkey, mopkey, sumex, agg, F, inv, M);
  k_wnorm<<<gN, TPB, 0, stream>>>(vox, inv, W, N);
}

// Round 7
// 443.852 us; speedup vs baseline: 7.5239x; 7.5239x over previous
//
#include <hip/hip_runtime.h>
#include <math.h>

#define C      4096                   // coarse buckets
#define VPB    32                     // voxels per bucket (C*VPB >= M)
#define BATCH  16384                  // gaussians per hist/transform block
#define TTPB   512                    // threads in hist/transform
#define RTPB   256                    // threads in breduce
#define GRP    16                     // lanes per voxel group
#define CAP    2048                   // bucket rows fast-path cap (mean 1024, sigma 32)
#define EPSF 1e-6f
#define LOG_G1 -2.3025850929940457f   /* log(0.1) */
#define LOGEPS -13.815510557964274f   /* log(1e-6) */
#define IDXMASK 0x07FFFFFFu           /* low 27 bits: gaussian idx (N < 2^27) */

__device__ __forceinline__ float gsum16(float x){
  #pragma unroll
  for (int k = 8; k >= 1; k >>= 1) x += __shfl_xor(x, k, 64);
  return x;
}
__device__ __forceinline__ float gmax16(float x){
  #pragma unroll
  for (int k = 8; k >= 1; k >>= 1) x = fmaxf(x, __shfl_xor(x, k, 64));
  return x;
}
__device__ __forceinline__ float score_from(float gt, float c, float t0){
  float g0 = fmaxf(c, EPSF);
  float dt = t0 - gt;
  // log(max(exp(sigma*dt^2),EPS))/T == max(sigma*dt^2, logEPS)/T exactly
  return fmaxf(LOG_G1 / (g0 * g0 + EPSF) * dt * dt, LOGEPS) / 0.07f;
}

// ---------- 1. per-block bucket histogram (LDS only, no global atomics) ----------
__global__ __launch_bounds__(TTPB)
void k_hist(const int* __restrict__ vox, unsigned* __restrict__ mat, int N){
  __shared__ unsigned h[C];
  for (int j = threadIdx.x; j < C; j += TTPB) h[j] = 0u;
  __syncthreads();
  size_t tbase = (size_t)blockIdx.x * BATCH;
  int nb = N - (int)tbase; if (nb > BATCH) nb = BATCH;
  for (int t = threadIdx.x; t < nb; t += TTPB)
    atomicAdd(&h[((unsigned)vox[tbase + t]) >> 5], 1u);
  __syncthreads();
  for (int j = threadIdx.x; j < C; j += TTPB)
    mat[(size_t)blockIdx.x * C + j] = h[j];
}

// ---------- 2. per-bucket totals (thread-per-bucket column sum, coalesced) ----------
__global__ void k_csum(const unsigned* __restrict__ mat, unsigned* __restrict__ btot, int nblk){
  int j = blockIdx.x * 256 + threadIdx.x;
  if (j >= C) return;
  unsigned s = 0;
  for (int b = 0; b < nblk; ++b) s += mat[(size_t)b * C + j];
  btot[j] = s;
}

// ---------- 3. exclusive scan of bucket totals (single block) ----------
__global__ void k_bscan(const unsigned* __restrict__ btot, unsigned* __restrict__ bbase){
  __shared__ unsigned sm[256];
  unsigned carry = 0;
  for (int base = 0; base < C; base += 256){
    int i = base + threadIdx.x;
    unsigned v = btot[i];
    sm[threadIdx.x] = v;
    __syncthreads();
    for (int off = 1; off < 256; off <<= 1){
      unsigned t = (threadIdx.x >= off) ? sm[threadIdx.x - off] : 0u;
      __syncthreads();
      sm[threadIdx.x] += t;
      __syncthreads();
    }
    bbase[i] = carry + sm[threadIdx.x] - v;
    carry += sm[255];
    __syncthreads();
  }
}

// ---------- 4. turn matrix into global (bucket,block) start offsets ----------
__global__ void k_apply(unsigned* __restrict__ mat, const unsigned* __restrict__ bbase, int nblk){
  int j = blockIdx.x * 256 + threadIdx.x;
  if (j >= C) return;
  unsigned run = bbase[j];
  for (int b = 0; b < nblk; ++b){
    unsigned o = mat[(size_t)b * C + j];
    mat[(size_t)b * C + j] = run;
    run += o;
  }
}

// ---------- 5. transform: linear payload + deterministic pair scatter ----------
// payload row (14 floats, 56B): [f0..f6, log(f7..f9), f10..f13]
__global__ __launch_bounds__(TTPB)
void k_transform(const float* __restrict__ feat, const float* __restrict__ conf,
                 const int* __restrict__ vox, const float* __restrict__ tt,
                 const unsigned* __restrict__ mat, unsigned* __restrict__ srank,
                 float* __restrict__ payload, float2* __restrict__ pairs, int N){
  __shared__ unsigned curs[C];        // 16 KB: global write cursor per bucket
  __shared__ float sf[TTPB * 15];     // 30 KB
  for (int j = threadIdx.x; j < C; j += TTPB)
    curs[j] = mat[(size_t)blockIdx.x * C + j];
  float t0 = tt[0];
  size_t tbase0 = (size_t)blockIdx.x * BATCH;
  for (int tile = 0; tile < BATCH / TTPB; ++tile){
    size_t tbase = tbase0 + (size_t)tile * TTPB;
    if (tbase >= (size_t)N) break;
    int nrow = N - (int)tbase; if (nrow > TTPB) nrow = TTPB;
    int nflt = nrow * 15;
    __syncthreads();                         // cursors ready / sf free
    if (nflt == TTPB * 15){
      const float4* g4 = (const float4*)(feat + tbase * 15);
      float4* s4 = (float4*)sf;
      #pragma unroll
      for (int k = 0; k < 4; ++k){
        int j = threadIdx.x + k * TTPB;
        if (j < TTPB * 15 / 4) s4[j] = g4[j];
      }
    } else {
      for (int j = threadIdx.x; j < nflt; j += TTPB)
        sf[j] = feat[tbase * 15 + j];
    }
    __syncthreads();
    int t = threadIdx.x;
    bool hav = (t < nrow);
    float r[15]; float score = 0.f; int v = 0;
    if (hav){
      #pragma unroll
      for (int c2 = 0; c2 < 15; ++c2) r[c2] = sf[t * 15 + c2];   // stride 15: conflict-free
      size_t i = tbase + t;
      score = score_from(r[14], conf[i], t0);
      r[7] = logf(fmaxf(r[7], 1e-6f));
      r[8] = logf(fmaxf(r[8], 1e-6f));
      r[9] = logf(fmaxf(r[9], 1e-6f));
      v = vox[i];
      #pragma unroll
      for (int c2 = 0; c2 < 14; ++c2) sf[t * 15 + c2] = r[c2];   // own row only
    }
    __syncthreads();
    // fully coalesced payload flush: nrow*7 float2
    float2* pay2 = (float2*)(payload + tbase * 14);
    int n2 = nrow * 7;
    for (int j = threadIdx.x; j < n2; j += TTPB){
      int rr = j / 7, q = j - rr * 7;
      pay2[j] = make_float2(sf[rr * 15 + 2 * q], sf[rr * 15 + 2 * q + 1]);
    }
    // pair scatter (LDS-rank, no global atomics) + linear srank
    if (hav){
      size_t i = tbase + t;
      unsigned gpos = atomicAdd(&curs[((unsigned)v) >> 5], 1u);
      pairs[gpos] = make_float2(score,
          __uint_as_float((unsigned)i | (((unsigned)v & 31u) << 27)));
      srank[i] = gpos;
    }
  }
}

// ---------- 6. per-bucket reduce: LDS counting sort + payload gather ----------
__global__ __launch_bounds__(RTPB)
void k_breduce(const float* __restrict__ payload, float2* __restrict__ pairs,
               const unsigned* __restrict__ bbase, const unsigned* __restrict__ btot,
               float* __restrict__ F, int M){
  __shared__ float          ssc[CAP];
  __shared__ unsigned       smeta[CAP];
  __shared__ unsigned short ssx[CAP];
  __shared__ unsigned lcnt[VPB + 1], lofs[VPB + 1];
  __shared__ float Fst[VPB * 15];
  __shared__ float mSt[VPB], iSt[VPB];

  int bk = blockIdx.x;
  unsigned base = bbase[bk], L = btot[bk];
  int v0 = bk * VPB;
  int g  = threadIdx.x / GRP;
  int sl = threadIdx.x & (GRP - 1);

  if (L <= CAP){
    for (unsigned j = threadIdx.x; j < L; j += RTPB){
      float2 pr = pairs[base + j];
      ssc[j]   = pr.x;
      smeta[j] = __float_as_uint(pr.y);
    }
    if (threadIdx.x <= VPB) lcnt[threadIdx.x] = 0u;
    __syncthreads();
    for (unsigned j = threadIdx.x; j < L; j += RTPB)
      atomicAdd(&lcnt[smeta[j] >> 27], 1u);
    __syncthreads();
    if (threadIdx.x == 0){
      unsigned s = 0;
      for (int k = 0; k < VPB; ++k){ lofs[k] = s; s += lcnt[k]; }
      lofs[VPB] = s;
    }
    __syncthreads();
    if (threadIdx.x < VPB) lcnt[threadIdx.x] = lofs[threadIdx.x];
    __syncthreads();
    for (unsigned j = threadIdx.x; j < L; j += RTPB){
      unsigned rk = atomicAdd(&lcnt[smeta[j] >> 27], 1u);
      ssx[rk] = (unsigned short)j;
    }
    __syncthreads();

    for (int vv = g; vv < VPB; vv += RTPB / GRP){
      unsigned s0 = lofs[vv], Lv = lofs[vv + 1] - s0;
      float m = -INFINITY;
      for (unsigned j = sl; j < Lv; j += GRP) m = fmaxf(m, ssc[ssx[s0 + j]]);
      m = gmax16(m);
      float se = 0.f, mop = -INFINITY;
      float a0=0,a1=0,a2=0,a3=0,a4=0,a5=0,a6=0,a7=0,a8=0,a9=0,a10=0,a11=0,a12=0,a13=0;
      for (unsigned j = sl; j < Lv; j += GRP){
        unsigned rj  = ssx[s0 + j];
        unsigned idx = smeta[rj] & IDXMASK;
        const float2* rp = (const float2*)payload + (size_t)idx * 7;
        float2 q0=rp[0], q1=rp[1], q2=rp[2], q3=rp[3], q4=rp[4], q5=rp[5], q6=rp[6];
        float e = expf(ssc[rj] - m);
        se += e;
        mop = fmaxf(mop, q3.x);                       // element 6 = opacity
        a0 += q0.x*e;  a1 += q0.y*e;  a2  += q1.x*e;  a3  += q1.y*e;
        a4 += q2.x*e;  a5 += q2.y*e;  a6  += q3.x*e;  a7  += q3.y*e;
        a8 += q4.x*e;  a9 += q4.y*e;  a10 += q5.x*e;  a11 += q5.y*e;
        a12 += q6.x*e; a13 += q6.y*e;
      }
      se  = gsum16(se);
      a0  = gsum16(a0);  a1  = gsum16(a1);  a2  = gsum16(a2);  a3  = gsum16(a3);
      a4  = gsum16(a4);  a5  = gsum16(a5);  a6  = gsum16(a6);  a7  = gsum16(a7);
      a8  = gsum16(a8);  a9  = gsum16(a9);  a10 = gsum16(a10); a11 = gsum16(a11);
      a12 = gsum16(a12); a13 = gsum16(a13);
      mop = gmax16(mop);
      if (sl == 0){
        bool  has = (Lv > 0u);
        float inv = has ? 1.0f / se : 0.0f;
        mSt[vv] = m;  iSt[vv] = inv;
        float maxop = has ? mop : 0.0f;
        float* f = &Fst[vv * 15];
        f[0] = a0*inv; f[1] = a1*inv; f[2] = a2*inv;
        f[3] = a3*inv; f[4] = a4*inv; f[5] = a5*inv;
        f[6] = 0.7f * maxop + 0.3f * (a6*inv);
        f[7] = expf(a7*inv); f[8] = expf(a8*inv); f[9] = expf(a9*inv);
        float r0 = a10*inv, r1 = a11*inv, r2 = a12*inv, r3 = a13*inv;
        float nrm  = sqrtf(r0*r0 + r1*r1 + r2*r2 + r3*r3);
        float rinv = 1.0f / fmaxf(nrm, 1e-6f);
        f[10] = r0*rinv; f[11] = r1*rinv; f[12] = r2*rinv; f[13] = r3*rinv;
        f[14] = 0.0f;
      }
    }
    __syncthreads();
    // weights written in place over OWN pairs chunk (dense 8B coalesced stores)
    for (unsigned j = threadIdx.x; j < L; j += RTPB){
      unsigned vv = smeta[j] >> 27;
      float w = expf(ssc[j] - mSt[vv]) * iSt[vv];
      pairs[base + j] = make_float2(w, 0.f);
    }
  } else {
    // ---- overflow fallback (statistically never): direct global filter ----
    for (int vv = g; vv < VPB; vv += RTPB / GRP){
      float m = -INFINITY;
      for (unsigned j = sl; j < L; j += GRP){
        float2 pr = pairs[base + j];
        if ((__float_as_uint(pr.y) >> 27) == (unsigned)vv) m = fmaxf(m, pr.x);
      }
      m = gmax16(m);
      float se = 0.f, mop = -INFINITY; unsigned nv = 0;
      float a0=0,a1=0,a2=0,a3=0,a4=0,a5=0,a6=0,a7=0,a8=0,a9=0,a10=0,a11=0,a12=0,a13=0;
      for (unsigned j = sl; j < L; j += GRP){
        float2 pr = pairs[base + j];
        unsigned meta = __float_as_uint(pr.y);
        if ((meta >> 27) != (unsigned)vv) continue;
        ++nv;
        unsigned idx = meta & IDXMASK;
        const float2* rp = (const float2*)payload + (size_t)idx * 7;
        float2 q0=rp[0], q1=rp[1], q2=rp[2], q3=rp[3], q4=rp[4], q5=rp[5], q6=rp[6];
        float e = expf(pr.x - m);
        se += e;
        mop = fmaxf(mop, q3.x);
        a0 += q0.x*e;  a1 += q0.y*e;  a2  += q1.x*e;  a3  += q1.y*e;
        a4 += q2.x*e;  a5 += q2.y*e;  a6  += q3.x*e;  a7  += q3.y*e;
        a8 += q4.x*e;  a9 += q4.y*e;  a10 += q5.x*e;  a11 += q5.y*e;
        a12 += q6.x*e; a13 += q6.y*e;
      }
      se  = gsum16(se);
      a0  = gsum16(a0);  a1  = gsum16(a1);  a2  = gsum16(a2);  a3  = gsum16(a3);
      a4  = gsum16(a4);  a5  = gsum16(a5);  a6  = gsum16(a6);  a7  = gsum16(a7);
      a8  = gsum16(a8);  a9  = gsum16(a9);  a10 = gsum16(a10); a11 = gsum16(a11);
      a12 = gsum16(a12); a13 = gsum16(a13);
      mop = gmax16(mop);
      nv  = (unsigned)gsum16((float)nv);
      if (sl == 0){
        bool  has = (nv > 0u);
        float inv = has ? 1.0f / se : 0.0f;
        mSt[vv] = m;  iSt[vv] = inv;
        float maxop = has ? mop : 0.0f;
        float* f = &Fst[vv * 15];
        f[0] = a0*inv; f[1] = a1*inv; f[2] = a2*inv;
        f[3] = a3*inv; f[4] = a4*inv; f[5] = a5*inv;
        f[6] = 0.7f * maxop + 0.3f * (a6*inv);
        f[7] = expf(a7*inv); f[8] = expf(a8*inv); f[9] = expf(a9*inv);
        float r0 = a10*inv, r1 = a11*inv, r2 = a12*inv, r3 = a13*inv;
        float nrm  = sqrtf(r0*r0 + r1*r1 + r2*r2 + r3*r3);
        float rinv = 1.0f / fmaxf(nrm, 1e-6f);
        f[10] = r0*rinv; f[11] = r1*rinv; f[12] = r2*rinv; f[13] = r3*rinv;
        f[14] = 0.0f;
      }
    }
    __syncthreads();
    for (unsigned j = threadIdx.x; j < L; j += RTPB){
      float2 pr = pairs[base + j];
      unsigned vv = __float_as_uint(pr.y) >> 27;
      pairs[base + j] = make_float2(expf(pr.x - mSt[vv]) * iSt[vv], 0.f);
    }
  }
  __syncthreads();
  int lim = M - v0; if (lim > VPB) lim = VPB;
  if (lim > 0)
    for (int j = threadIdx.x; j < lim * 15; j += RTPB)
      F[(size_t)v0 * 15 + j] = Fst[j];
}

// ---------- 7. W: linear write, random L3-hot gather ----------
__global__ void k_wfinal(const unsigned* __restrict__ srank, const float2* __restrict__ pairs,
                         float* __restrict__ W, int N){
  int i = blockIdx.x * 256 + threadIdx.x;
  if (i >= N) return;
  W[i] = pairs[srank[i]].x;
}

extern "C" void kernel_launch(void* const* d_in, const int* in_sizes, int n_in,
                              void* d_out, int out_size, void* d_ws, size_t ws_size,
                              hipStream_t stream) {
  const float* feat = (const float*)d_in[0];
  const int*   vox  = (const int*)  d_in[1];
  const float* tt   = (const float*)d_in[3];
  const float* conf = (const float*)d_in[4];

  int N = in_sizes[0] / 15;
  int M = (out_size - N) / 15;
  int NBLK = (N + BATCH - 1) / BATCH;

  float* F = (float*)d_out;                      // fused gaussians: M*15
  float* W = (float*)d_out + (size_t)M * 15;     // weights: N

  unsigned* mat   = (unsigned*)d_ws;             // NBLK*C
  unsigned* btot  = mat  + (size_t)NBLK * C;     // C
  unsigned* bbase = btot + C;                    // C
  unsigned* srank = bbase + C;                   // N
  size_t head = ((size_t)NBLK * C + 2 * (size_t)C + (size_t)N + 15) & ~(size_t)15;
  float*  payload = (float*)d_ws + head;         // 14*N floats (56B rows)
  float2* pairs   = (float2*)(payload + (size_t)14 * N);   // N float2

  k_hist     <<<NBLK,  TTPB, 0, stream>>>(vox, mat, N);
  k_csum     <<<C/256, 256,  0, stream>>>(mat, btot, NBLK);
  k_bscan    <<<1,     256,  0, stream>>>(btot, bbase);
  k_apply    <<<C/256, 256,  0, stream>>>(mat, bbase, NBLK);
  k_transform<<<NBLK,  TTPB, 0, stream>>>(feat, conf, vox, tt, mat, srank, payload, pairs, N);
  k_breduce  <<<C,     RTPB, 0, stream>>>(payload, pairs, bbase, btot, F, M);
  k_wfinal   <<<(N + 255)/256, 256, 0, stream>>>(srank, pairs, W, N);
}